// Round 11
// baseline (532.026 us; speedup 1.0000x reference)
//
#include <hip/hip_runtime.h>
#include <math.h>

// Problem constants: x [B=16, C=64, H=256, W=256] fp32
#define BB   16
#define CC   64
#define HH_  256
#define WW_  256
#define HW   (HH_ * WW_)        // 65536
#define CHW  (CC * HW)          // 4194304
#define BH   8                  // output rows per block (band height)
#define HALO 3                  // conv radius
#define PR   (BH + 2*HALO)      // 14 pooled rows staged in LDS
#define NBANDS (HH_ / BH)       // 32
#define NBLK (BB * NBANDS)      // 512 blocks

// Native clang vector type for __builtin_nontemporal_load/store.
typedef float vfloat4 __attribute__((ext_vector_type(4)));

// Fused kernel: one block = one 8-row band of one image.
//  Phase 1: channel mean/max pooling of the band's rows +/-3 halo -> LDS.
//  Phase 2: 7x7 conv + bias + sigmoid entirely from LDS (att in registers).
//  Phase 3: re-read band's x (L2/L3-hot: touched microseconds ago in phase 1)
//           and write out = x * att with non-temporal load/store.
// This reads x from HBM once (halo rows shared with the concurrently-running
// neighbor block via L3) instead of the old two-pass double read.
__global__ __launch_bounds__(256) void fused_kernel(const float* __restrict__ x,
                                                    const float* __restrict__ cw,
                                                    const float* __restrict__ cb,
                                                    float* __restrict__ out) {
    __shared__ float sw[99];            // [0..48] avg taps, [49..97] max taps, [98] bias
    __shared__ float ap[PR][WW_];       // pooled avg rows (14 x 256 floats = 14 KiB)
    __shared__ float mp[PR][WW_];       // pooled max rows

    const int tid = threadIdx.x;
    if (tid < 99) sw[tid] = (tid < 98) ? cw[tid] : cb[0];

    const int bid  = blockIdx.x;
    const int b    = bid >> 5;                  // image index
    const int band = bid & (NBANDS - 1);        // band within image
    const int R0   = band * BH;                 // first output row

    const float4* xb4 = (const float4*)x + (size_t)b * (CHW / 4);

    // ---- Phase 1: pool halo'd band rows into LDS ----
    // 14 rows x 64 col-quads = 896 jobs over 256 threads (4 sweeps, last partial).
    for (int j = tid; j < PR * 64; j += 256) {
        const int i   = j >> 6;                 // LDS row 0..13
        const int q   = j & 63;                 // col quad
        const int row = R0 - HALO + i;          // image row (may be out of range)
        float4 a = {0.f, 0.f, 0.f, 0.f};        // out-of-image pooled halo = 0 (zero pad)
        float4 m = {0.f, 0.f, 0.f, 0.f};
        if (row >= 0 && row < HH_) {
            const float4* p = xb4 + row * 64 + q;
            float4 s  = {0.f, 0.f, 0.f, 0.f};
            float4 mm = {-INFINITY, -INFINITY, -INFINITY, -INFINITY};
            #pragma unroll 8
            for (int c = 0; c < CC; ++c) {
                float4 v = p[c * (HW / 4)];
                s.x += v.x; s.y += v.y; s.z += v.z; s.w += v.w;
                mm.x = fmaxf(mm.x, v.x); mm.y = fmaxf(mm.y, v.y);
                mm.z = fmaxf(mm.z, v.z); mm.w = fmaxf(mm.w, v.w);
            }
            const float inv = 1.0f / 64.0f;
            a.x = s.x * inv; a.y = s.y * inv; a.z = s.z * inv; a.w = s.w * inv;
            m = mm;
        }
        *(float4*)&ap[i][q * 4] = a;
        *(float4*)&mp[i][q * 4] = m;
    }
    __syncthreads();

    const float bias = sw[98];

    // ---- Phase 2 + 3: conv from LDS, then stream x*att ----
    // k = tid + s*256 walks the band's 512 col-quads; lanes are consecutive
    // quads within one row -> fully coalesced global access in phase 3.
    for (int s = 0; s < 2; ++s) {
        const int k   = tid + s * 256;
        const int rl  = k >> 6;                 // band-local row 0..7
        const int q   = k & 63;                 // col quad
        const int row = R0 + rl;

        float acc0 = bias, acc1 = bias, acc2 = bias, acc3 = bias;
        #pragma unroll
        for (int dy = -3; dy <= 3; ++dy) {
            const int li = rl + HALO + dy;      // LDS row, always in [0, PR)
            const float4* a4 = (const float4*)&ap[li][0];
            const float4* m4 = (const float4*)&mp[li][0];
            const float4 z = {0.f, 0.f, 0.f, 0.f};
            float4 aL = (q > 0)  ? a4[q - 1] : z;   // col zero-padding at image edge
            float4 aC = a4[q];
            float4 aR = (q < 63) ? a4[q + 1] : z;
            float4 mL = (q > 0)  ? m4[q - 1] : z;
            float4 mC = m4[q];
            float4 mR = (q < 63) ? m4[q + 1] : z;
            float av[12] = {aL.x,aL.y,aL.z,aL.w, aC.x,aC.y,aC.z,aC.w, aR.x,aR.y,aR.z,aR.w};
            float mv[12] = {mL.x,mL.y,mL.z,mL.w, mC.x,mC.y,mC.z,mC.w, mR.x,mR.y,mR.z,mR.w};
            const float* wr = sw + (dy + 3) * 7;
            #pragma unroll
            for (int kx = 0; kx < 7; ++kx) {
                float wa = wr[kx];
                float wm = wr[49 + kx];
                int t = 1 + kx;
                acc0 = fmaf(av[t + 0], wa, acc0);  acc0 = fmaf(mv[t + 0], wm, acc0);
                acc1 = fmaf(av[t + 1], wa, acc1);  acc1 = fmaf(mv[t + 1], wm, acc1);
                acc2 = fmaf(av[t + 2], wa, acc2);  acc2 = fmaf(mv[t + 2], wm, acc2);
                acc3 = fmaf(av[t + 3], wa, acc3);  acc3 = fmaf(mv[t + 3], wm, acc3);
            }
        }

        const float att0 = 1.f / (1.f + __expf(-acc0));
        const float att1 = 1.f / (1.f + __expf(-acc1));
        const float att2 = 1.f / (1.f + __expf(-acc2));
        const float att3 = 1.f / (1.f + __expf(-acc3));

        const vfloat4* xr = (const vfloat4*)x  + (size_t)b * (CHW / 4) + row * 64 + q;
        vfloat4*       ow = (vfloat4*)out      + (size_t)b * (CHW / 4) + row * 64 + q;
        #pragma unroll 4
        for (int c = 0; c < CC; ++c) {
            vfloat4 v = __builtin_nontemporal_load(xr + c * (HW / 4)); // last use of x
            vfloat4 r;
            r.x = v.x * att0; r.y = v.y * att1; r.z = v.z * att2; r.w = v.w * att3;
            __builtin_nontemporal_store(r, ow + c * (HW / 4));         // out never re-read
        }
    }
}

extern "C" void kernel_launch(void* const* d_in, const int* in_sizes, int n_in,
                              void* d_out, int out_size, void* d_ws, size_t ws_size,
                              hipStream_t stream) {
    const float* x  = (const float*)d_in[0];
    const float* cw = (const float*)d_in[1];   // [1,2,7,7] = 98 floats
    const float* cb = (const float*)d_in[2];   // [1]
    float* out = (float*)d_out;

    fused_kernel<<<dim3(NBLK), dim3(256), 0, stream>>>(x, cw, cb, out);
}

// Round 12
// 499.770 us; speedup vs baseline: 1.0645x; 1.0645x over previous
//
#include <hip/hip_runtime.h>
#include <math.h>

// Problem constants: x [B=16, C=64, H=256, W=256] fp32
#define BB   16
#define CC   64
#define HH_  256
#define WW_  256
#define HW   (HH_ * WW_)        // 65536
#define CHW  (CC * HW)          // 4194304
#define BH   8                  // output rows per block (band height)
#define HALO 3                  // conv radius
#define PR   (BH + 2*HALO)      // 14 pooled rows staged in LDS
#define NBANDS (HH_ / BH)       // 32
#define NBLK (BB * NBANDS)      // 512 blocks
#define NT_  512                // threads per block (8 waves): 2 blocks/CU = 16 waves/CU

// Native clang vector type for __builtin_nontemporal_load/store.
typedef float vfloat4 __attribute__((ext_vector_type(4)));

// Fused kernel: one block = one 8-row band of one image.
//  Phase 1: channel mean/max pooling of the band's rows +/-3 halo -> LDS.
//  Phase 2: 7x7 conv + bias + sigmoid entirely from LDS (att in registers).
//  Phase 3: re-read band's x (L2/L3-hot from phase 1) and write out = x*att (NT).
//
// R11 post-mortem: traffic was near-ideal (FETCH 354 MB = x once + 1.32x halo
// tax; reuse worked) but the kernel was latency-bound at 22% occupancy
// (512 blocks x 4 waves = 8 waves/CU, VALUBusy 4.5%, 1.1-2.7 TB/s).
// Fix: 512-thread blocks -> 16 waves/CU at identical traffic and LDS.
__global__ __launch_bounds__(NT_) void fused_kernel(const float* __restrict__ x,
                                                    const float* __restrict__ cw,
                                                    const float* __restrict__ cb,
                                                    float* __restrict__ out) {
    __shared__ float sw[99];            // [0..48] avg taps, [49..97] max taps, [98] bias
    __shared__ float ap[PR][WW_];       // pooled avg rows (14 x 256 floats = 14 KiB)
    __shared__ float mp[PR][WW_];       // pooled max rows

    const int tid = threadIdx.x;
    if (tid < 99) sw[tid] = (tid < 98) ? cw[tid] : cb[0];

    const int bid  = blockIdx.x;
    const int b    = bid >> 5;                  // image index
    const int band = bid & (NBANDS - 1);        // band within image
    const int R0   = band * BH;                 // first output row

    const float4* xb4 = (const float4*)x + (size_t)b * (CHW / 4);

    // ---- Phase 1: pool halo'd band rows into LDS ----
    // 14 rows x 64 col-quads = 896 jobs over 512 threads (2 sweeps, last partial).
    for (int j = tid; j < PR * 64; j += NT_) {
        const int i   = j >> 6;                 // LDS row 0..13
        const int q   = j & 63;                 // col quad
        const int row = R0 - HALO + i;          // image row (may be out of range)
        float4 a = {0.f, 0.f, 0.f, 0.f};        // out-of-image pooled halo = 0 (zero pad)
        float4 m = {0.f, 0.f, 0.f, 0.f};
        if (row >= 0 && row < HH_) {
            const float4* p = xb4 + row * 64 + q;
            float4 s  = {0.f, 0.f, 0.f, 0.f};
            float4 mm = {-INFINITY, -INFINITY, -INFINITY, -INFINITY};
            #pragma unroll 8
            for (int c = 0; c < CC; ++c) {
                float4 v = p[c * (HW / 4)];
                s.x += v.x; s.y += v.y; s.z += v.z; s.w += v.w;
                mm.x = fmaxf(mm.x, v.x); mm.y = fmaxf(mm.y, v.y);
                mm.z = fmaxf(mm.z, v.z); mm.w = fmaxf(mm.w, v.w);
            }
            const float inv = 1.0f / 64.0f;
            a.x = s.x * inv; a.y = s.y * inv; a.z = s.z * inv; a.w = s.w * inv;
            m = mm;
        }
        *(float4*)&ap[i][q * 4] = a;
        *(float4*)&mp[i][q * 4] = m;
    }
    __syncthreads();

    const float bias = sw[98];

    // ---- Phase 2 + 3: conv from LDS, then stream x*att ----
    // Exactly one job per thread: 512 col-quads per band, 512 threads.
    {
        const int rl  = tid >> 6;               // band-local row 0..7
        const int q   = tid & 63;               // col quad
        const int row = R0 + rl;

        float acc0 = bias, acc1 = bias, acc2 = bias, acc3 = bias;
        #pragma unroll
        for (int dy = -3; dy <= 3; ++dy) {
            const int li = rl + HALO + dy;      // LDS row, always in [0, PR)
            const float4* a4 = (const float4*)&ap[li][0];
            const float4* m4 = (const float4*)&mp[li][0];
            const float4 z = {0.f, 0.f, 0.f, 0.f};
            float4 aL = (q > 0)  ? a4[q - 1] : z;   // col zero-padding at image edge
            float4 aC = a4[q];
            float4 aR = (q < 63) ? a4[q + 1] : z;
            float4 mL = (q > 0)  ? m4[q - 1] : z;
            float4 mC = m4[q];
            float4 mR = (q < 63) ? m4[q + 1] : z;
            float av[12] = {aL.x,aL.y,aL.z,aL.w, aC.x,aC.y,aC.z,aC.w, aR.x,aR.y,aR.z,aR.w};
            float mv[12] = {mL.x,mL.y,mL.z,mL.w, mC.x,mC.y,mC.z,mC.w, mR.x,mR.y,mR.z,mR.w};
            const float* wr = sw + (dy + 3) * 7;
            #pragma unroll
            for (int kx = 0; kx < 7; ++kx) {
                float wa = wr[kx];
                float wm = wr[49 + kx];
                int t = 1 + kx;
                acc0 = fmaf(av[t + 0], wa, acc0);  acc0 = fmaf(mv[t + 0], wm, acc0);
                acc1 = fmaf(av[t + 1], wa, acc1);  acc1 = fmaf(mv[t + 1], wm, acc1);
                acc2 = fmaf(av[t + 2], wa, acc2);  acc2 = fmaf(mv[t + 2], wm, acc2);
                acc3 = fmaf(av[t + 3], wa, acc3);  acc3 = fmaf(mv[t + 3], wm, acc3);
            }
        }

        const float att0 = 1.f / (1.f + __expf(-acc0));
        const float att1 = 1.f / (1.f + __expf(-acc1));
        const float att2 = 1.f / (1.f + __expf(-acc2));
        const float att3 = 1.f / (1.f + __expf(-acc3));

        const vfloat4* xr = (const vfloat4*)x  + (size_t)b * (CHW / 4) + row * 64 + q;
        vfloat4*       ow = (vfloat4*)out      + (size_t)b * (CHW / 4) + row * 64 + q;
        #pragma unroll 4
        for (int c = 0; c < CC; ++c) {
            vfloat4 v = __builtin_nontemporal_load(xr + c * (HW / 4)); // last use of x
            vfloat4 r;
            r.x = v.x * att0; r.y = v.y * att1; r.z = v.z * att2; r.w = v.w * att3;
            __builtin_nontemporal_store(r, ow + c * (HW / 4));         // out never re-read
        }
    }
}

extern "C" void kernel_launch(void* const* d_in, const int* in_sizes, int n_in,
                              void* d_out, int out_size, void* d_ws, size_t ws_size,
                              hipStream_t stream) {
    const float* x  = (const float*)d_in[0];
    const float* cw = (const float*)d_in[1];   // [1,2,7,7] = 98 floats
    const float* cb = (const float*)d_in[2];   // [1]
    float* out = (float*)d_out;

    fused_kernel<<<dim3(NBLK), dim3(NT_), 0, stream>>>(x, cw, cb, out);
}